// Round 13
// baseline (421.681 us; speedup 1.0000x reference)
//
#include <hip/hip_runtime.h>
#include <hip/hip_bf16.h>
#include <hip/hip_cooperative_groups.h>
#include <math.h>

namespace cg = cooperative_groups;

#define D_MODEL 512
#define D_LOW   64
#define NBINS   39
#define LOG2E   1.4426950408889634f
#define LN2     0.6931471805599453f

typedef __attribute__((ext_vector_type(8))) short short8;
typedef __attribute__((ext_vector_type(4))) float floatx4;

// ===========================================================================
// Cooperative mega-kernel (primary path). Grid = 512 x 256, needs only
// 2 blocks/CU co-resident (launch_bounds(256,2); ~14.4 KB LDS, VGPR<=256).
// Phases: prep+tbin | lnproj+wprep | pair (6 units/block) | finalize.
// ===========================================================================
__global__ __launch_bounds__(256, 2) void mega_kernel(
    const float* __restrict__ h_res,
    const float* __restrict__ x_true,
    const float* __restrict__ pmask,
    const float* __restrict__ ln_w, const float* __restrict__ ln_b,
    const float* __restrict__ wu_w, const float* __restrict__ wu_b,
    const float* __restrict__ wv_w, const float* __restrict__ wv_b,
    const float* __restrict__ wb_w, const float* __restrict__ wb_b,
    __hip_bfloat16* __restrict__ Vbf,
    signed char* __restrict__ tbg,
    short* __restrict__ wfragbuf,
    __hip_bfloat16* __restrict__ w2bf,
    float* __restrict__ w2sum, float* __restrict__ b2,
    float* __restrict__ part,
    float* __restrict__ out,
    int N) {
  cg::grid_group grid = cg::this_grid();
  __shared__ float Urow[16][D_LOW];
  __shared__ float wsh[NBINS * 65];
  __shared__ float red[32];
  const int nb  = gridDim.x;              // 512
  const int bid = blockIdx.x;
  const int tid = threadIdx.x;
  const int wave = tid >> 6, lane = tid & 63;
  const int q = lane >> 4, ln16 = lane & 15;
  const int B  = 2;
  const int BN = B * N;

  // ============ Phase 1: prep (blocks 0..127) + tbin (grid-stride) =========
  if (bid < 128) {
    const int o = bid;
    const bool isU = (o < 64);
    const float* wrow = isU ? (wu_w + o * D_MODEL) : (wv_w + (o - 64) * D_MODEL);
    const float scale = isU ? LOG2E : 1.0f;
    float s1 = 0.f, s2 = 0.f;
    #pragma unroll
    for (int cc = 0; cc < 2; ++cc) {
      const int c = tid + cc * 256;
      const float w  = wrow[c];
      const float w2 = w * ln_w[c] * scale;
      const __hip_bfloat16 hb = __float2bfloat16(w2);
      w2bf[o * D_MODEL + c] = hb;
      s1 += __bfloat162float(hb);
      s2 += w * ln_b[c];
    }
    #pragma unroll
    for (int off = 32; off; off >>= 1) {
      s1 += __shfl_xor(s1, off);
      s2 += __shfl_xor(s2, off);
    }
    if (lane == 0) { red[wave] = s1; red[4 + wave] = s2; }
    __syncthreads();
    if (tid == 0) {
      w2sum[o] = red[0] + red[1] + red[2] + red[3];
      const float ss2 = red[4] + red[5] + red[6] + red[7];
      b2[o] = scale * ((isU ? wu_b[o] : wv_b[o - 64]) + ss2);
    }
  }
  for (int row = bid; row < BN; row += nb) {
    const int b = (row >= N) ? 1 : 0;
    const int i = row - b * N;
    const float xi0 = x_true[row * 3 + 0];
    const float xi1 = x_true[row * 3 + 1];
    const float xi2 = x_true[row * 3 + 2];
    const float pmi = pmask[row];
    const float BW  = (22.0f - 2.0f) / 38.0f;
    signed char* tbp = tbg + (size_t)b * N * N + (size_t)i * N;
    for (int j = tid; j < N; j += 256) {
      const int rowj = b * N + j;
      const float dx = xi0 - x_true[rowj * 3 + 0];
      const float dy = xi1 - x_true[rowj * 3 + 1];
      const float dz = xi2 - x_true[rowj * 3 + 2];
      const float d  = sqrtf(dx * dx + dy * dy + dz * dz);
      int tb = (int)((d - 2.0f) / BW);
      tb = tb < 0 ? 0 : (tb > NBINS - 1 ? NBINS - 1 : tb);
      tbp[j] = (pmi * pmask[rowj] > 0.f) ? (signed char)tb : (signed char)-1;
    }
  }
  __threadfence();
  grid.sync();

  // ============ Phase 2: lnproj + wprep (blocks 0..BN/16-1) ================
  if (bid < BN / 16) {
    for (int e = tid; e < NBINS * D_LOW; e += 256) {
      wsh[(e >> 6) * 65 + (e & 63)] = wb_w[e];
    }
    const int row0 = bid * 16;
    const float* hp = h_res + (size_t)(row0 + ln16) * D_MODEL + q * 8;
    short8 abf[16];
    float sum = 0.f, ssq = 0.f;
    #pragma unroll
    for (int kc = 0; kc < 16; ++kc) {
      const floatx4 x0 = *reinterpret_cast<const floatx4*>(hp + kc * 32);
      const floatx4 x1 = *reinterpret_cast<const floatx4*>(hp + kc * 32 + 4);
      short8 a;
      #pragma unroll
      for (int e = 0; e < 4; ++e) {
        sum += x0[e]; ssq += x0[e] * x0[e];
        const __hip_bfloat16 hb = __float2bfloat16(x0[e]);
        a[e] = *reinterpret_cast<const short*>(&hb);
      }
      #pragma unroll
      for (int e = 0; e < 4; ++e) {
        sum += x1[e]; ssq += x1[e] * x1[e];
        const __hip_bfloat16 hb = __float2bfloat16(x1[e]);
        a[4 + e] = *reinterpret_cast<const short*>(&hb);
      }
      abf[kc] = a;
    }
    sum += __shfl_xor(sum, 16); sum += __shfl_xor(sum, 32);
    ssq += __shfl_xor(ssq, 16); ssq += __shfl_xor(ssq, 32);
    const float mu  = sum * (1.0f / (float)D_MODEL);
    const float var = ssq * (1.0f / (float)D_MODEL) - mu * mu;
    const float rs  = rsqrtf(var + 1e-5f);
    float mu_r[4], rs_r[4];
    #pragma unroll
    for (int r = 0; r < 4; ++r) {
      mu_r[r] = __shfl(mu, q * 4 + r);
      rs_r[r] = __shfl(rs, q * 4 + r);
    }

    const int obase = wave * 32;
    const int out0 = obase + ln16;
    const int out1 = obase + 16 + ln16;
    const short* wp = reinterpret_cast<const short*>(w2bf);
    floatx4 acc0 = (floatx4){0.f, 0.f, 0.f, 0.f};
    floatx4 acc1 = (floatx4){0.f, 0.f, 0.f, 0.f};
    #pragma unroll
    for (int kc = 0; kc < 16; ++kc) {
      const short8 b0 = *reinterpret_cast<const short8*>(
          wp + (size_t)out0 * D_MODEL + kc * 32 + q * 8);
      const short8 b1 = *reinterpret_cast<const short8*>(
          wp + (size_t)out1 * D_MODEL + kc * 32 + q * 8);
      acc0 = __builtin_amdgcn_mfma_f32_16x16x32_bf16(abf[kc], b0, acc0, 0, 0, 0);
      acc1 = __builtin_amdgcn_mfma_f32_16x16x32_bf16(abf[kc], b1, acc1, 0, 0, 0);
    }

    #pragma unroll
    for (int nt = 0; nt < 2; ++nt) {
      const int out_ = nt ? out1 : out0;
      const floatx4 a = nt ? acc1 : acc0;
      const float ws = w2sum[out_];
      const float bb = b2[out_];
      #pragma unroll
      for (int r = 0; r < 4; ++r) {
        const int rloc = q * 4 + r;
        const float val = rs_r[r] * a[r] - mu_r[r] * rs_r[r] * ws + bb;
        if (out_ < 64) {
          Urow[rloc][out_] = val;
        } else {
          Vbf[(size_t)(row0 + rloc) * D_LOW + (out_ - 64)] = __float2bfloat16(val);
        }
      }
    }
    __syncthreads();

    #pragma unroll
    for (int rr = 0; rr < 4; ++rr) {
      const int rloc = wave * 4 + rr;
      const int rowi = row0 + rloc;
      float u[16];
      #pragma unroll
      for (int s = 0; s < 2; ++s)
        #pragma unroll
        for (int e = 0; e < 8; ++e) u[s * 8 + e] = Urow[rloc][s * 32 + q * 8 + e];
      short* outp = wfragbuf + (size_t)rowi * 6 * 64 * 8;
      #pragma unroll
      for (int t = 0; t < 3; ++t) {
        const int n = t * 16 + ln16;
        #pragma unroll
        for (int s = 0; s < 2; ++s) {
          short8 f;
          #pragma unroll
          for (int e = 0; e < 8; ++e) {
            const float w = (n < NBINS) ? wsh[n * 65 + s * 32 + q * 8 + e] : 0.f;
            const float v = u[s * 8 + e] * w;
            const __hip_bfloat16 hb = __float2bfloat16(v);
            f[e] = *reinterpret_cast<const short*>(&hb);
          }
          *reinterpret_cast<short8*>(outp + ((size_t)(t * 2 + s) * 64 + lane) * 8) = f;
        }
      }
    }
  }
  __threadfence();
  grid.sync();

  // ============ Phase 3: pair — 6 units/block, unit = (i, b, half) =========
  floatx4 bias_init[3];
  #pragma unroll
  for (int t = 0; t < 3; ++t)
    #pragma unroll
    for (int r = 0; r < 4; ++r) {
      const int bin = t * 16 + q * 4 + r;
      bias_init[t][r] = (bin < NBINS) ? LOG2E * wb_b[bin] : -INFINITY;
    }
  const int q4 = q * 4;
  float ce_acc[2]  = {0.f, 0.f};
  float cnt_acc[2] = {0.f, 0.f};

  for (int k = 0; k < 6; ++k) {
    const int u = bid + k * nb;            // < 4*N = 3072
    if (u >= 4 * N) break;
    const int i    = u >> 2;
    const int b    = (u >> 1) & 1;
    const int half = u & 1;
    const int rowi = b * N + i;

    short8 wfrag[3][2];
    {
      const short* wfp = wfragbuf + (size_t)rowi * 6 * 64 * 8;
      #pragma unroll
      for (int t = 0; t < 3; ++t)
        #pragma unroll
        for (int s = 0; s < 2; ++s)
          wfrag[t][s] = *reinterpret_cast<const short8*>(
              wfp + ((size_t)(t * 2 + s) * 64 + lane) * 8);
    }
    const short* Vp = reinterpret_cast<const short*>(Vbf) + (size_t)b * N * D_LOW;
    const signed char* tbp = tbg + (size_t)b * N * N + (size_t)i * N;
    const int jbase = half * 384 + wave * 96;

    float ce_u = 0.f, cnt_u = 0.f;
    for (int g = 0; g < 3; ++g) {
      const int jb = jbase + g * 32;
      short8 v[2][2];
      int tbv[2];
      #pragma unroll
      for (int tt = 0; tt < 2; ++tt) {
        const size_t jr = jb + tt * 16 + ln16;
        v[tt][0] = *reinterpret_cast<const short8*>(Vp + jr * D_LOW + q * 8);
        v[tt][1] = *reinterpret_cast<const short8*>(Vp + jr * D_LOW + 32 + q * 8);
        tbv[tt]  = (int)tbp[jr];
      }

      #pragma unroll
      for (int tt = 0; tt < 2; ++tt) {
        floatx4 f[3];
        #pragma unroll
        for (int t = 0; t < 3; ++t) {
          floatx4 a = bias_init[t];
          a = __builtin_amdgcn_mfma_f32_16x16x32_bf16(wfrag[t][0], v[tt][0], a, 0, 0, 0);
          a = __builtin_amdgcn_mfma_f32_16x16x32_bf16(wfrag[t][1], v[tt][1], a, 0, 0, 0);
          f[t] = a;
        }
        const int tb  = tbv[tt];
        const int tbq = tb - q4;
        float s0 = 0.f, s1 = 0.f, s2 = 0.f, s3 = 0.f, lt = 0.f;
        #pragma unroll
        for (int t = 0; t < 3; ++t) {
          const floatx4 fv = f[t];
          s0 += __builtin_amdgcn_exp2f(fv[0]);
          s1 += __builtin_amdgcn_exp2f(fv[1]);
          s2 += __builtin_amdgcn_exp2f(fv[2]);
          s3 += __builtin_amdgcn_exp2f(fv[3]);
          lt += (tbq == t * 16 + 0) ? fv[0] : 0.f;
          lt += (tbq == t * 16 + 1) ? fv[1] : 0.f;
          lt += (tbq == t * 16 + 2) ? fv[2] : 0.f;
          lt += (tbq == t * 16 + 3) ? fv[3] : 0.f;
        }
        float ssum = (s0 + s1) + (s2 + s3);
        ssum += __shfl_xor(ssum, 16); ssum += __shfl_xor(ssum, 32);
        // x4-quad identity: Σ_quads [log2(ssum) - 4*lt_local] = 4*CE/ln2
        const float ok = (tb >= 0) ? 1.f : 0.f;
        ce_u  += ok * LN2 * (__builtin_amdgcn_logf(ssum) - 4.0f * lt);
        cnt_u += ok;
      }
    }
    ce_acc[0]  += (b == 0) ? ce_u : 0.f;
    ce_acc[1]  += (b == 1) ? ce_u : 0.f;
    cnt_acc[0] += (b == 0) ? cnt_u : 0.f;
    cnt_acc[1] += (b == 1) ? cnt_u : 0.f;
  }

  #pragma unroll
  for (int off = 32; off; off >>= 1) {
    ce_acc[0]  += __shfl_xor(ce_acc[0], off);
    ce_acc[1]  += __shfl_xor(ce_acc[1], off);
    cnt_acc[0] += __shfl_xor(cnt_acc[0], off);
    cnt_acc[1] += __shfl_xor(cnt_acc[1], off);
  }
  if (lane == 0) {
    float* ps = part + ((size_t)bid * 4 + wave) * 4;
    ps[0] = ce_acc[0]; ps[1] = cnt_acc[0];
    ps[2] = ce_acc[1]; ps[3] = cnt_acc[1];
  }
  __threadfence();
  grid.sync();

  // ============ Phase 4: finalize (block 0) ================================
  if (bid == 0) {
    float ce0 = 0.f, cn0 = 0.f, ce1 = 0.f, cn1 = 0.f;
    for (int e = tid; e < nb * 4; e += 256) {
      const float* ps = part + (size_t)e * 4;
      ce0 += ps[0]; cn0 += ps[1]; ce1 += ps[2]; cn1 += ps[3];
    }
    #pragma unroll
    for (int off = 32; off; off >>= 1) {
      ce0 += __shfl_xor(ce0, off); cn0 += __shfl_xor(cn0, off);
      ce1 += __shfl_xor(ce1, off); cn1 += __shfl_xor(cn1, off);
    }
    if (lane == 0) {
      red[wave * 4 + 0] = ce0; red[wave * 4 + 1] = cn0;
      red[wave * 4 + 2] = ce1; red[wave * 4 + 3] = cn1;
    }
    __syncthreads();
    if (tid == 0) {
      float tce0 = 0.f, tcn0 = 0.f, tce1 = 0.f, tcn1 = 0.f;
      #pragma unroll
      for (int w = 0; w < 4; ++w) {
        tce0 += red[w * 4 + 0]; tcn0 += red[w * 4 + 1];
        tce1 += red[w * 4 + 2]; tcn1 += red[w * 4 + 3];
      }
      float loss = 0.f, vc = 0.f;
      if (tcn0 > 0.f) { loss += tce0 / fmaxf(tcn0, 1.f); vc += 1.f; }
      if (tcn1 > 0.f) { loss += tce1 / fmaxf(tcn1, 1.f); vc += 1.f; }
      out[0] = (vc > 0.f) ? loss / vc : 0.f;
    }
  }
}

// ===========================================================================
// Fallback path: the round-8 proven 4-kernel pipeline (118.5 us), verbatim.
// Used only if the cooperative launch is refused by the runtime.
// ===========================================================================
__global__ __launch_bounds__(256) void fb_prep_tbin_kernel(
    const float* __restrict__ ln_w, const float* __restrict__ ln_b,
    const float* __restrict__ wu_w, const float* __restrict__ wu_b,
    const float* __restrict__ wv_w, const float* __restrict__ wv_b,
    const float* __restrict__ x_true, const float* __restrict__ pmask,
    __hip_bfloat16* __restrict__ w2bf, float* __restrict__ w2sum,
    float* __restrict__ b2, signed char* __restrict__ tbg, int N) {
  const int tid = threadIdx.x;
  if ((int)blockIdx.x >= 128) {
    const int p = blockIdx.x - 128;
    const int b = (p >= N) ? 1 : 0;
    const int i = p - b * N;
    const int rowi = b * N + i;
    const float xi0 = x_true[rowi * 3 + 0];
    const float xi1 = x_true[rowi * 3 + 1];
    const float xi2 = x_true[rowi * 3 + 2];
    const float pmi = pmask[rowi];
    const float BW  = (22.0f - 2.0f) / 38.0f;
    signed char* tbp = tbg + (size_t)b * N * N + (size_t)i * N;
    for (int j = tid; j < N; j += 256) {
      const int rowj = b * N + j;
      const float dx = xi0 - x_true[rowj * 3 + 0];
      const float dy = xi1 - x_true[rowj * 3 + 1];
      const float dz = xi2 - x_true[rowj * 3 + 2];
      const float d  = sqrtf(dx * dx + dy * dy + dz * dz);
      int tb = (int)((d - 2.0f) / BW);
      tb = tb < 0 ? 0 : (tb > NBINS - 1 ? NBINS - 1 : tb);
      tbp[j] = (pmi * pmask[rowj] > 0.f) ? (signed char)tb : (signed char)-1;
    }
    return;
  }
  __shared__ float red[8];
  const int o = blockIdx.x;
  const bool isU = (o < 64);
  const float* wrow = isU ? (wu_w + o * D_MODEL) : (wv_w + (o - 64) * D_MODEL);
  const float scale = isU ? LOG2E : 1.0f;
  float s1 = 0.f, s2 = 0.f;
  #pragma unroll
  for (int cc = 0; cc < 2; ++cc) {
    const int c = tid + cc * 256;
    const float w  = wrow[c];
    const float w2 = w * ln_w[c] * scale;
    const __hip_bfloat16 hb = __float2bfloat16(w2);
    w2bf[o * D_MODEL + c] = hb;
    s1 += __bfloat162float(hb);
    s2 += w * ln_b[c];
  }
  #pragma unroll
  for (int off = 32; off; off >>= 1) {
    s1 += __shfl_xor(s1, off);
    s2 += __shfl_xor(s2, off);
  }
  const int wave = tid >> 6, lane = tid & 63;
  if (lane == 0) { red[wave] = s1; red[4 + wave] = s2; }
  __syncthreads();
  if (tid == 0) {
    w2sum[o] = red[0] + red[1] + red[2] + red[3];
    const float ss2 = red[4] + red[5] + red[6] + red[7];
    b2[o] = scale * ((isU ? wu_b[o] : wv_b[o - 64]) + ss2);
  }
}

__global__ __launch_bounds__(64) void fb_lnproj_kernel(
    const float* __restrict__ h_res, const __hip_bfloat16* __restrict__ w2bf,
    const float* __restrict__ w2sum, const float* __restrict__ b2,
    float* __restrict__ U, __hip_bfloat16* __restrict__ Vbf, int N) {
  const int lane = threadIdx.x;
  const int q = lane >> 4, ln16 = lane & 15;
  const int rt = blockIdx.x >> 2, og = blockIdx.x & 3;
  const int row0 = rt * 16;
  const float* hp = h_res + (size_t)(row0 + ln16) * D_MODEL + q * 8;
  short8 abf[16];
  float sum = 0.f, ssq = 0.f;
  #pragma unroll
  for (int kc = 0; kc < 16; ++kc) {
    const floatx4 x0 = *reinterpret_cast<const floatx4*>(hp + kc * 32);
    const floatx4 x1 = *reinterpret_cast<const floatx4*>(hp + kc * 32 + 4);
    short8 a;
    #pragma unroll
    for (int e = 0; e < 4; ++e) {
      sum += x0[e]; ssq += x0[e] * x0[e];
      const __hip_bfloat16 hb = __float2bfloat16(x0[e]);
      a[e] = *reinterpret_cast<const short*>(&hb);
    }
    #pragma unroll
    for (int e = 0; e < 4; ++e) {
      sum += x1[e]; ssq += x1[e] * x1[e];
      const __hip_bfloat16 hb = __float2bfloat16(x1[e]);
      a[4 + e] = *reinterpret_cast<const short*>(&hb);
    }
    abf[kc] = a;
  }
  sum += __shfl_xor(sum, 16); sum += __shfl_xor(sum, 32);
  ssq += __shfl_xor(ssq, 16); ssq += __shfl_xor(ssq, 32);
  const float mu  = sum * (1.0f / (float)D_MODEL);
  const float var = ssq * (1.0f / (float)D_MODEL) - mu * mu;
  const float rs  = rsqrtf(var + 1e-5f);
  float mu_r[4], rs_r[4];
  #pragma unroll
  for (int r = 0; r < 4; ++r) {
    mu_r[r] = __shfl(mu, q * 4 + r);
    rs_r[r] = __shfl(rs, q * 4 + r);
  }
  const int obase = og * 32;
  const int out0 = obase + ln16;
  const int out1 = obase + 16 + ln16;
  const short* wp = reinterpret_cast<const short*>(w2bf);
  floatx4 acc0 = (floatx4){0.f, 0.f, 0.f, 0.f};
  floatx4 acc1 = (floatx4){0.f, 0.f, 0.f, 0.f};
  #pragma unroll
  for (int kc = 0; kc < 16; ++kc) {
    const short8 b0 = *reinterpret_cast<const short8*>(
        wp + (size_t)out0 * D_MODEL + kc * 32 + q * 8);
    const short8 b1 = *reinterpret_cast<const short8*>(
        wp + (size_t)out1 * D_MODEL + kc * 32 + q * 8);
    acc0 = __builtin_amdgcn_mfma_f32_16x16x32_bf16(abf[kc], b0, acc0, 0, 0, 0);
    acc1 = __builtin_amdgcn_mfma_f32_16x16x32_bf16(abf[kc], b1, acc1, 0, 0, 0);
  }
  #pragma unroll
  for (int nt = 0; nt < 2; ++nt) {
    const int out = nt ? out1 : out0;
    const floatx4 a = nt ? acc1 : acc0;
    const float ws = w2sum[out];
    const float bb = b2[out];
    #pragma unroll
    for (int r = 0; r < 4; ++r) {
      const int rowg = row0 + q * 4 + r;
      const float val = rs_r[r] * a[r] - mu_r[r] * rs_r[r] * ws + bb;
      if (out < 64) {
        U[(size_t)rowg * D_LOW + out] = val;
      } else {
        Vbf[(size_t)rowg * D_LOW + (out - 64)] = __float2bfloat16(val);
      }
    }
  }
}

__global__ __launch_bounds__(256) void fb_wprep_kernel(
    const float* __restrict__ U, const float* __restrict__ wb_w,
    short* __restrict__ wfragbuf, int BN) {
  __shared__ float wsh[NBINS * 65];
  const int tid = threadIdx.x;
  for (int e = tid; e < NBINS * D_LOW; e += 256) {
    wsh[(e >> 6) * 65 + (e & 63)] = wb_w[e];
  }
  __syncthreads();
  const int wave = tid >> 6, lane = tid & 63;
  const int q = lane >> 4, ln16 = lane & 15;
  const int rowi = blockIdx.x * 4 + wave;
  const float* Up = U + (size_t)rowi * D_LOW;
  float u[16];
  #pragma unroll
  for (int s = 0; s < 2; ++s)
    #pragma unroll
    for (int e = 0; e < 8; ++e) u[s * 8 + e] = Up[s * 32 + q * 8 + e];
  short* outp = wfragbuf + (size_t)rowi * 6 * 64 * 8;
  #pragma unroll
  for (int t = 0; t < 3; ++t) {
    const int n = t * 16 + ln16;
    #pragma unroll
    for (int s = 0; s < 2; ++s) {
      short8 f;
      #pragma unroll
      for (int e = 0; e < 8; ++e) {
        const float w = (n < NBINS) ? wsh[n * 65 + s * 32 + q * 8 + e] : 0.f;
        const float v = u[s * 8 + e] * w;
        const __hip_bfloat16 hb = __float2bfloat16(v);
        f[e] = *reinterpret_cast<const short*>(&hb);
      }
      *reinterpret_cast<short8*>(outp + ((size_t)(t * 2 + s) * 64 + lane) * 8) = f;
    }
  }
}

__global__ __launch_bounds__(256) void fb_pair_mfma_kernel(
    const short* __restrict__ wfragbuf,
    const __hip_bfloat16* __restrict__ Vbf,
    const float* __restrict__ wb_b,
    const signed char* __restrict__ tbg,
    float* __restrict__ part, int N) {
  __shared__ float rbuf[8];
  const int i    = blockIdx.x;
  const int b    = blockIdx.y >> 1;
  const int half = blockIdx.y & 1;
  const int tid  = threadIdx.x;
  const int wave = tid >> 6, lane = tid & 63;
  const int q = lane >> 4, ln16 = lane & 15;
  const int rowi = b * N + i;
  short8 wfrag[3][2];
  {
    const short* wfp = wfragbuf + (size_t)rowi * 6 * 64 * 8;
    #pragma unroll
    for (int t = 0; t < 3; ++t)
      #pragma unroll
      for (int s = 0; s < 2; ++s)
        wfrag[t][s] = *reinterpret_cast<const short8*>(
            wfp + ((size_t)(t * 2 + s) * 64 + lane) * 8);
  }
  floatx4 bias_init[3];
  #pragma unroll
  for (int t = 0; t < 3; ++t)
    #pragma unroll
    for (int r = 0; r < 4; ++r) {
      const int bin = t * 16 + q * 4 + r;
      bias_init[t][r] = (bin < NBINS) ? LOG2E * wb_b[bin] : -INFINITY;
    }
  const short* Vp = reinterpret_cast<const short*>(Vbf) + (size_t)b * N * D_LOW;
  const signed char* tbp = tbg + (size_t)b * N * N + (size_t)i * N;
  const int jbase = half * 384 + wave * 96;
  const int q4 = q * 4;
  float ce_sum = 0.f, cnt_sum = 0.f;
  for (int g = 0; g < 3; ++g) {
    const int jb = jbase + g * 32;
    short8 v[2][2];
    int tbv[2];
    #pragma unroll
    for (int tt = 0; tt < 2; ++tt) {
      const size_t jr = jb + tt * 16 + ln16;
      v[tt][0] = *reinterpret_cast<const short8*>(Vp + jr * D_LOW + q * 8);
      v[tt][1] = *reinterpret_cast<const short8*>(Vp + jr * D_LOW + 32 + q * 8);
      tbv[tt]  = (int)tbp[jr];
    }
    #pragma unroll
    for (int tt = 0; tt < 2; ++tt) {
      floatx4 f[3];
      #pragma unroll
      for (int t = 0; t < 3; ++t) {
        floatx4 a = bias_init[t];
        a = __builtin_amdgcn_mfma_f32_16x16x32_bf16(wfrag[t][0], v[tt][0], a, 0, 0, 0);
        a = __builtin_amdgcn_mfma_f32_16x16x32_bf16(wfrag[t][1], v[tt][1], a, 0, 0, 0);
        f[t] = a;
      }
      const int tb  = tbv[tt];
      const int tbq = tb - q4;
      float s0 = 0.f, s1 = 0.f, s2 = 0.f, s3 = 0.f, lt = 0.f;
      #pragma unroll
      for (int t = 0; t < 3; ++t) {
        const floatx4 fv = f[t];
        s0 += __builtin_amdgcn_exp2f(fv[0]);
        s1 += __builtin_amdgcn_exp2f(fv[1]);
        s2 += __builtin_amdgcn_exp2f(fv[2]);
        s3 += __builtin_amdgcn_exp2f(fv[3]);
        lt += (tbq == t * 16 + 0) ? fv[0] : 0.f;
        lt += (tbq == t * 16 + 1) ? fv[1] : 0.f;
        lt += (tbq == t * 16 + 2) ? fv[2] : 0.f;
        lt += (tbq == t * 16 + 3) ? fv[3] : 0.f;
      }
      float ssum = (s0 + s1) + (s2 + s3);
      ssum += __shfl_xor(ssum, 16); ssum += __shfl_xor(ssum, 32);
      const float ok = (tb >= 0) ? 1.f : 0.f;
      ce_sum  += ok * LN2 * (__builtin_amdgcn_logf(ssum) - 4.0f * lt);
      cnt_sum += ok;
    }
  }
  #pragma unroll
  for (int off = 32; off; off >>= 1) {
    ce_sum  += __shfl_xor(ce_sum, off);
    cnt_sum += __shfl_xor(cnt_sum, off);
  }
  if (lane == 0) { rbuf[wave] = ce_sum; rbuf[4 + wave] = cnt_sum; }
  __syncthreads();
  if (tid == 0) {
    const size_t slot = ((size_t)(b * 2 + half) * N + i) * 2;
    part[slot + 0] = rbuf[0] + rbuf[1] + rbuf[2] + rbuf[3];
    part[slot + 1] = rbuf[4] + rbuf[5] + rbuf[6] + rbuf[7];
  }
}

__global__ __launch_bounds__(256) void fb_finalize_kernel(
    const float* __restrict__ part, float* __restrict__ out, int N, int B) {
  __shared__ float red[8];
  const int tid = threadIdx.x, wave = tid >> 6, lane = tid & 63;
  float loss = 0.f, vcount = 0.f;
  for (int b = 0; b < B; ++b) {
    float ce = 0.f, cnt = 0.f;
    for (int e = tid; e < 2 * N; e += 256) {
      const size_t base = ((size_t)b * 2 * N + e) * 2;
      ce  += part[base + 0];
      cnt += part[base + 1];
    }
    #pragma unroll
    for (int off = 32; off; off >>= 1) {
      ce  += __shfl_xor(ce, off);
      cnt += __shfl_xor(cnt, off);
    }
    if (lane == 0) { red[wave] = ce; red[4 + wave] = cnt; }
    __syncthreads();
    if (tid == 0) {
      const float s = red[0] + red[1] + red[2] + red[3];
      const float c = red[4] + red[5] + red[6] + red[7];
      if (c > 0.f) { loss += s / fmaxf(c, 1.f); vcount += 1.f; }
    }
    __syncthreads();
  }
  if (tid == 0) out[0] = (vcount > 0.f) ? loss / vcount : 0.f;
}

extern "C" void kernel_launch(void* const* d_in, const int* in_sizes, int n_in,
                              void* d_out, int out_size, void* d_ws, size_t ws_size,
                              hipStream_t stream) {
  const float* h_res  = (const float*)d_in[0];
  const float* x_true = (const float*)d_in[1];
  const float* pmask  = (const float*)d_in[2];
  const float* ln_w   = (const float*)d_in[3];
  const float* ln_b   = (const float*)d_in[4];
  const float* wu_w   = (const float*)d_in[5];
  const float* wu_b   = (const float*)d_in[6];
  const float* wv_w   = (const float*)d_in[7];
  const float* wv_b   = (const float*)d_in[8];
  const float* wb_w   = (const float*)d_in[9];
  const float* wb_b   = (const float*)d_in[10];

  const int B  = 2;
  int N  = in_sizes[2] / B;
  const int BN = B * N;

  // ws: Vbf bf16[BN*64] | U f32[BN*64] | part f32[16*BN] | tbg s8[B*N*N]
  //     | wfragbuf short[BN*6*64*8] | w2bf bf16[128*512] | w2sum | b2
  __hip_bfloat16* Vbf = (__hip_bfloat16*)d_ws;
  float* U = (float*)(Vbf + (size_t)BN * D_LOW);
  float* part = U + (size_t)BN * D_LOW;
  signed char* tbg = (signed char*)(part + 16 * (size_t)BN);
  short* wfragbuf = (short*)(tbg + (size_t)B * N * N);
  __hip_bfloat16* w2bf = (__hip_bfloat16*)(wfragbuf + (size_t)BN * 6 * 64 * 8);
  float* w2sum = (float*)(w2bf + 128 * D_MODEL);
  float* b2    = w2sum + 128;
  float* outp  = (float*)d_out;

  void* args[] = {
    (void*)&h_res, (void*)&x_true, (void*)&pmask,
    (void*)&ln_w, (void*)&ln_b, (void*)&wu_w, (void*)&wu_b,
    (void*)&wv_w, (void*)&wv_b, (void*)&wb_w, (void*)&wb_b,
    (void*)&Vbf, (void*)&tbg, (void*)&wfragbuf, (void*)&w2bf,
    (void*)&w2sum, (void*)&b2, (void*)&part, (void*)&outp, (void*)&N
  };
  hipError_t err = hipLaunchCooperativeKernel(
      mega_kernel, dim3(512), dim3(256), args, 0, stream);

  if (err != hipSuccess) {
    // Deterministic fallback: the round-8 proven 4-kernel pipeline.
    fb_prep_tbin_kernel<<<128 + BN, 256, 0, stream>>>(
        ln_w, ln_b, wu_w, wu_b, wv_w, wv_b, x_true, pmask,
        w2bf, w2sum, b2, tbg, N);
    fb_lnproj_kernel<<<(BN / 16) * 4, 64, 0, stream>>>(h_res, w2bf, w2sum, b2,
                                                       U, Vbf, N);
    fb_wprep_kernel<<<BN / 4, 256, 0, stream>>>(U, wb_w, wfragbuf, BN);
    fb_pair_mfma_kernel<<<dim3(N, 2 * B), 256, 0, stream>>>(wfragbuf, Vbf,
                                                            wb_b, tbg, part, N);
    fb_finalize_kernel<<<1, 256, 0, stream>>>(part, (float*)d_out, N, B);
  }
}